// Round 17
// baseline (161.081 us; speedup 1.0000x reference)
//
#include <hip/hip_runtime.h>
#include <hip/hip_bf16.h>

typedef __attribute__((ext_vector_type(4))) int   i32x4;
typedef __attribute__((ext_vector_type(8))) int   i32x8;
typedef __attribute__((ext_vector_type(16))) float f32x16;

#define C_DIM 512
#define SCALE 1.6487212707001282f            // exp(0.5)
#define S2LOG (SCALE * 1.4426950408889634f)  // exp(0.5) * log2(e)

// -------- Kernel A: L2-normalize rows -> fp8 e4m3 in HALF-MAJOR fragment layout;
//          exact fp32 diag; zero sumexp.
// Fragment (rb,kb) = 2048B at base (rb*8+kb)*2048, stored as two 1KB halves:
//   half h (h=0: k bytes [.. +16), h=1: [+16..+32)) at base + h*1024 + lane*16,
//   lane l = 32*(k64half) + (row&31).  GEMM loads are perfect 1KB bursts.
__global__ __launch_bounds__(128) void cossim_normalize(
    const float* __restrict__ pred, const float* __restrict__ target,
    unsigned char* __restrict__ p8, unsigned char* __restrict__ t8,
    float* __restrict__ diag, float* __restrict__ sumexp) {
  const int n = blockIdx.x;
  const int t = threadIdx.x;  // 128 threads, 4 floats each = 512
  const float4* p4 = (const float4*)(pred + (size_t)n * C_DIM);
  const float4* q4 = (const float4*)(target + (size_t)n * C_DIM);
  float4 a = p4[t];
  float4 b = q4[t];
  float ssp = a.x*a.x + a.y*a.y + a.z*a.z + a.w*a.w;
  float sst = b.x*b.x + b.y*b.y + b.z*b.z + b.w*b.w;
  float dt  = a.x*b.x + a.y*b.y + a.z*b.z + a.w*b.w;
  #pragma unroll
  for (int off = 32; off > 0; off >>= 1) {
    ssp += __shfl_down(ssp, off);
    sst += __shfl_down(sst, off);
    dt  += __shfl_down(dt,  off);
  }
  __shared__ float red[3][2];
  const int wid = t >> 6;
  if ((t & 63) == 0) { red[0][wid] = ssp; red[1][wid] = sst; red[2][wid] = dt; }
  __syncthreads();
  const float tp = red[0][0] + red[0][1];
  const float tt = red[1][0] + red[1][1];
  const float td = red[2][0] + red[2][1];
  const float rnp = 1.0f / fmaxf(sqrtf(tp), 1e-12f);
  const float rnt = 1.0f / fmaxf(sqrtf(tt), 1e-12f);

  unsigned pw = (unsigned)__builtin_amdgcn_cvt_pk_fp8_f32(a.x * rnp, a.y * rnp, 0, false);
  pw = (unsigned)__builtin_amdgcn_cvt_pk_fp8_f32(a.z * rnp, a.w * rnp, (int)pw, true);
  unsigned tw = (unsigned)__builtin_amdgcn_cvt_pk_fp8_f32(b.x * rnt, b.y * rnt, 0, false);
  tw = (unsigned)__builtin_amdgcn_cvt_pk_fp8_f32(b.z * rnt, b.w * rnt, (int)tw, true);

  // half-major fragment-tiled destination for the 4B word at k-byte t*4 of row n:
  //   kb = t>>4, k64half = (t>>3)&1, h = (t>>2)&1, lane = 32*k64half + (n&31)
  const size_t off8 = ((size_t)((n >> 5) * 8 + (t >> 4))) * 2048 +
                      (size_t)((t >> 2) & 1) * 1024 +
                      (size_t)(((t >> 3) & 1) * 32 + (n & 31)) * 16 + (t & 3) * 4;
  *(unsigned*)(p8 + off8) = pw;
  *(unsigned*)(t8 + off8) = tw;

  if (t == 0) {
    diag[n] = td * rnp * rnt * SCALE;  // exact fp32 diagonal, already scaled
    sumexp[n] = 0.0f;
  }
}

// -------- Kernel B: 128x128-tile fp8 MX-MFMA NT-GEMM (scales=1.0), 256 threads,
//          ZERO-LDS / ZERO-BARRIER main loop, perfect-1KB-burst fragment loads,
//          3 blocks/CU (VGPR ~128 <= 170 budget) for TLP latency hiding.
__global__ __launch_bounds__(256, 3) void cossim_gemm_lse(
    const unsigned char* __restrict__ P, const unsigned char* __restrict__ T,
    float* __restrict__ sumexp) {
  __shared__ float lds_rs[2][128];  // epilogue row-sum only

  const int tid  = threadIdx.x;
  const int lane = tid & 63;
  const int w    = tid >> 6;   // 0..3
  const int wr   = w >> 1;     // wave row 0..1 (owns 64 C-rows)
  const int wc   = w & 1;      // wave col 0..1 (owns 64 C-cols)

  // L2-locality supertile swizzle, bijective on 4096 blocks = 64by x 64bx tiles.
  const int xcd  = blockIdx.x & 7;
  const int slot = blockIdx.x >> 3;       // 0..511
  const int q    = slot >> 6;             // 0..7: round (4 x 2 supertile grid)
  const int v    = slot & 63;             // 0..63: position in 8x8 supertile
  const int by   = (xcd >> 2) * 32 + (q >> 1) * 8 + (v >> 3);  // 0..63
  const int bx   = (xcd & 3) * 16 + (q & 1) * 8 + (v & 7);     // 0..63
  const int brow = by * 128;
  const int bcol = bx * 128;

  // Fragment base pointers (half-major): base (rb*8+s)*2048; lane offset lane*16.
  const unsigned char* pa0 = P + ((size_t)(by * 4 + wr * 2 + 0) * 8) * 2048 + lane * 16;
  const unsigned char* pa1 = P + ((size_t)(by * 4 + wr * 2 + 1) * 8) * 2048 + lane * 16;
  const unsigned char* pb0 = T + ((size_t)(bx * 4 + wc * 2 + 0) * 8) * 2048 + lane * 16;
  const unsigned char* pb1 = T + ((size_t)(bx * 4 + wc * 2 + 1) * 8) * 2048 + lane * 16;

  auto LD = [](const unsigned char* p) -> i32x8 {
    const i32x4 lo = *(const i32x4*)p;            // 1KB burst (half 0)
    const i32x4 hi = *(const i32x4*)(p + 1024);   // 1KB burst (half 1)
    return __builtin_shufflevector(lo, hi, 0, 1, 2, 3, 4, 5, 6, 7);
  };

  f32x16 acc[2][2] = {};

  i32x8 a0 = LD(pa0), a1 = LD(pa1), b0 = LD(pb0), b1 = LD(pb1);

  #pragma unroll
  for (int s = 0; s < 8; ++s) {
    i32x8 na0, na1, nb0, nb1;
    if (s + 1 < 8) {
      const int o = (s + 1) * 2048;
      na0 = LD(pa0 + o); na1 = LD(pa1 + o);
      nb0 = LD(pb0 + o); nb1 = LD(pb1 + o);
    }
    __builtin_amdgcn_s_setprio(1);
    acc[0][0] = __builtin_amdgcn_mfma_scale_f32_32x32x64_f8f6f4(
        a0, b0, acc[0][0], 0, 0, 0, 127, 0, 127);
    acc[0][1] = __builtin_amdgcn_mfma_scale_f32_32x32x64_f8f6f4(
        a0, b1, acc[0][1], 0, 0, 0, 127, 0, 127);
    acc[1][0] = __builtin_amdgcn_mfma_scale_f32_32x32x64_f8f6f4(
        a1, b0, acc[1][0], 0, 0, 0, 127, 0, 127);
    acc[1][1] = __builtin_amdgcn_mfma_scale_f32_32x32x64_f8f6f4(
        a1, b1, acc[1][1], 0, 0, 0, 127, 0, 127);
    __builtin_amdgcn_s_setprio(0);
    if (s + 1 < 8) { a0 = na0; a1 = na1; b0 = nb0; b1 = nb1; }
  }

  // ---- epilogue: exp + row-sum. C/D 32x32: col=lane&31, row=(r&3)+8*(r>>2)+4*(lane>>5)
  #pragma unroll
  for (int m = 0; m < 2; ++m) {
    #pragma unroll
    for (int r = 0; r < 16; ++r) {
      float x = exp2f(acc[m][0][r] * S2LOG) + exp2f(acc[m][1][r] * S2LOG);
      x += __shfl_xor(x, 1);
      x += __shfl_xor(x, 2);
      x += __shfl_xor(x, 4);
      x += __shfl_xor(x, 8);
      x += __shfl_xor(x, 16);
      if ((lane & 31) == 0)
        lds_rs[wc][wr * 64 + m * 32 + (r & 3) + 8 * (r >> 2) + (lane >> 5) * 4] = x;
    }
  }
  __syncthreads();
  if (tid < 128) {
    atomicAdd(&sumexp[brow + tid], lds_rs[0][tid] + lds_rs[1][tid]);
  }
}

// -------- Kernel C: loss = mean(log(sumexp) - diag), 1024 threads, float4 loads
__global__ __launch_bounds__(1024) void cossim_loss(
    const float* __restrict__ sumexp, const float* __restrict__ diag,
    float* __restrict__ out, int N) {
  const int tid = threadIdx.x;
  const float4* s4 = (const float4*)sumexp;
  const float4* d4 = (const float4*)diag;
  float s = 0.0f;
  for (int i = tid; i < N / 4; i += 1024) {
    float4 a = s4[i];
    float4 b = d4[i];
    s += (logf(a.x) - b.x) + (logf(a.y) - b.y) + (logf(a.z) - b.z) + (logf(a.w) - b.w);
  }
  #pragma unroll
  for (int off = 32; off > 0; off >>= 1) s += __shfl_down(s, off);
  __shared__ float red[16];
  if ((tid & 63) == 0) red[tid >> 6] = s;
  __syncthreads();
  if (tid == 0) {
    float t = 0.0f;
    #pragma unroll
    for (int i = 0; i < 16; ++i) t += red[i];
    out[0] = t / (float)N;
  }
}

extern "C" void kernel_launch(void* const* d_in, const int* in_sizes, int n_in,
                              void* d_out, int out_size, void* d_ws, size_t ws_size,
                              hipStream_t stream) {
  const int C = C_DIM;
  const int N = in_sizes[0] / C;  // 8192
  const float* pred   = (const float*)d_in[0];
  const float* target = (const float*)d_in[1];
  float* out = (float*)d_out;

  char* ws = (char*)d_ws;
  unsigned char* p8 = (unsigned char*)ws;                    // 4 MB fragment-tiled
  unsigned char* t8 = (unsigned char*)(ws + (size_t)N * C);  // 4 MB fragment-tiled
  float* diag   = (float*)(ws + (size_t)2 * N * C);
  float* sumexp = diag + N;

  cossim_normalize<<<N, 128, 0, stream>>>(pred, target, p8, t8, diag, sumexp);
  const int nblk = (N / 128) * (N / 128);  // 4096
  cossim_gemm_lse<<<nblk, 256, 0, stream>>>(p8, t8, sumexp);
  cossim_loss<<<1, 1024, 0, stream>>>(sumexp, diag, out, N);
}

// Round 21
// 86.473 us; speedup vs baseline: 1.8628x; 1.8628x over previous
//
#include <hip/hip_runtime.h>
#include <hip/hip_bf16.h>

typedef __attribute__((ext_vector_type(4))) int   i32x4;
typedef __attribute__((ext_vector_type(8))) int   i32x8;
typedef __attribute__((ext_vector_type(16))) float f32x16;

#define C_DIM 512
#define SCALE 1.6487212707001282f            // exp(0.5)
#define S2LOG (SCALE * 1.4426950408889634f)  // exp(0.5) * log2(e)

// -------- Kernel A: L2-normalize rows -> fp8 e4m3 in HALF-MAJOR fragment layout;
//          exact fp32 diag; zero sumexp.
// Fragment (rb,kb) = 2048B at base (rb*8+kb)*2048, stored as two 1KB halves:
//   half h at base + h*1024 + lane*16, lane = 32*(k64half) + (row&31).
__global__ __launch_bounds__(128) void cossim_normalize_v2(
    const float* __restrict__ pred, const float* __restrict__ target,
    unsigned char* __restrict__ p8, unsigned char* __restrict__ t8,
    float* __restrict__ diag, float* __restrict__ sumexp) {
  const int n = blockIdx.x;
  const int t = threadIdx.x;  // 128 threads, 4 floats each = 512
  const float4* p4 = (const float4*)(pred + (size_t)n * C_DIM);
  const float4* q4 = (const float4*)(target + (size_t)n * C_DIM);
  float4 a = p4[t];
  float4 b = q4[t];
  float ssp = a.x*a.x + a.y*a.y + a.z*a.z + a.w*a.w;
  float sst = b.x*b.x + b.y*b.y + b.z*b.z + b.w*b.w;
  float dt  = a.x*b.x + a.y*b.y + a.z*b.z + a.w*b.w;
  #pragma unroll
  for (int off = 32; off > 0; off >>= 1) {
    ssp += __shfl_down(ssp, off);
    sst += __shfl_down(sst, off);
    dt  += __shfl_down(dt,  off);
  }
  __shared__ float red[3][2];
  const int wid = t >> 6;
  if ((t & 63) == 0) { red[0][wid] = ssp; red[1][wid] = sst; red[2][wid] = dt; }
  __syncthreads();
  const float tp = red[0][0] + red[0][1];
  const float tt = red[1][0] + red[1][1];
  const float td = red[2][0] + red[2][1];
  const float rnp = 1.0f / fmaxf(sqrtf(tp), 1e-12f);
  const float rnt = 1.0f / fmaxf(sqrtf(tt), 1e-12f);

  unsigned pw = (unsigned)__builtin_amdgcn_cvt_pk_fp8_f32(a.x * rnp, a.y * rnp, 0, false);
  pw = (unsigned)__builtin_amdgcn_cvt_pk_fp8_f32(a.z * rnp, a.w * rnp, (int)pw, true);
  unsigned tw = (unsigned)__builtin_amdgcn_cvt_pk_fp8_f32(b.x * rnt, b.y * rnt, 0, false);
  tw = (unsigned)__builtin_amdgcn_cvt_pk_fp8_f32(b.z * rnt, b.w * rnt, (int)tw, true);

  const size_t off8 = ((size_t)((n >> 5) * 8 + (t >> 4))) * 2048 +
                      (size_t)((t >> 2) & 1) * 1024 +
                      (size_t)(((t >> 3) & 1) * 32 + (n & 31)) * 16 + (t & 3) * 4;
  *(unsigned*)(p8 + off8) = pw;
  *(unsigned*)(t8 + off8) = tw;

  if (t == 0) {
    diag[n] = td * rnp * rnt * SCALE;  // exact fp32 diagonal, already scaled
    sumexp[n] = 0.0f;
  }
}

// -------- Kernel B: 128x128-tile fp8 MX-MFMA NT-GEMM (scales=1.0), 512 threads,
//          8 waves x 32x64 acc (32 regs) -> 4 waves/SIMD, 16 waves/CU TLP.
//          ZERO-LDS / ZERO-BARRIER free-run loop, 1KB-burst fragment loads.
__global__ __launch_bounds__(512, 4) void cossim_gemm_lse_v2(
    const unsigned char* __restrict__ P, const unsigned char* __restrict__ T,
    float* __restrict__ sumexp) {
  __shared__ float lds_rs[2][128];  // epilogue row-sum only

  const int tid  = threadIdx.x;
  const int lane = tid & 63;
  const int w    = tid >> 6;   // 0..7
  const int wr   = w >> 1;     // wave row 0..3 (owns 32 C-rows)
  const int wc   = w & 1;      // wave col 0..1 (owns 64 C-cols)

  // L2-locality supertile swizzle, bijective on 4096 blocks = 64by x 64bx tiles.
  const int xcd  = blockIdx.x & 7;
  const int slot = blockIdx.x >> 3;       // 0..511
  const int q    = slot >> 6;             // 0..7: round (4 x 2 supertile grid)
  const int v    = slot & 63;             // 0..63: position in 8x8 supertile
  const int by   = (xcd >> 2) * 32 + (q >> 1) * 8 + (v >> 3);  // 0..63
  const int bx   = (xcd & 3) * 16 + (q & 1) * 8 + (v & 7);     // 0..63
  const int brow = by * 128;

  // Fragment base pointers (half-major): base (rb*8+s)*2048; lane offset lane*16.
  const unsigned char* pa  = P + ((size_t)(by * 4 + wr) * 8) * 2048 + lane * 16;
  const unsigned char* pb0 = T + ((size_t)(bx * 4 + wc * 2 + 0) * 8) * 2048 + lane * 16;
  const unsigned char* pb1 = T + ((size_t)(bx * 4 + wc * 2 + 1) * 8) * 2048 + lane * 16;

  auto LD = [](const unsigned char* p) -> i32x8 {
    const i32x4 lo = *(const i32x4*)p;            // 1KB burst (half 0)
    const i32x4 hi = *(const i32x4*)(p + 1024);   // 1KB burst (half 1)
    return __builtin_shufflevector(lo, hi, 0, 1, 2, 3, 4, 5, 6, 7);
  };

  f32x16 acc0 = {}, acc1 = {};

  i32x8 a0 = LD(pa), b0 = LD(pb0), b1 = LD(pb1);

  #pragma unroll
  for (int s = 0; s < 8; ++s) {
    i32x8 na, nb0, nb1;
    if (s + 1 < 8) {
      const int o = (s + 1) * 2048;
      na = LD(pa + o); nb0 = LD(pb0 + o); nb1 = LD(pb1 + o);
    }
    __builtin_amdgcn_s_setprio(1);
    acc0 = __builtin_amdgcn_mfma_scale_f32_32x32x64_f8f6f4(
        a0, b0, acc0, 0, 0, 0, 127, 0, 127);
    acc1 = __builtin_amdgcn_mfma_scale_f32_32x32x64_f8f6f4(
        a0, b1, acc1, 0, 0, 0, 127, 0, 127);
    __builtin_amdgcn_s_setprio(0);
    if (s + 1 < 8) { a0 = na; b0 = nb0; b1 = nb1; }
  }

  // ---- epilogue: exp + row-sum. C/D 32x32: col=lane&31, row=(r&3)+8*(r>>2)+4*(lane>>5)
  #pragma unroll
  for (int r = 0; r < 16; ++r) {
    float x = exp2f(acc0[r] * S2LOG) + exp2f(acc1[r] * S2LOG);
    x += __shfl_xor(x, 1);
    x += __shfl_xor(x, 2);
    x += __shfl_xor(x, 4);
    x += __shfl_xor(x, 8);
    x += __shfl_xor(x, 16);
    if ((lane & 31) == 0)
      lds_rs[wc][wr * 32 + (r & 3) + 8 * (r >> 2) + (lane >> 5) * 4] = x;
  }
  __syncthreads();
  if (tid < 128) {
    atomicAdd(&sumexp[brow + tid], lds_rs[0][tid] + lds_rs[1][tid]);
  }
}

// -------- Kernel C: loss = mean(log(sumexp) - diag), 1024 threads, float4 loads
__global__ __launch_bounds__(1024) void cossim_loss_v2(
    const float* __restrict__ sumexp, const float* __restrict__ diag,
    float* __restrict__ out, int N) {
  const int tid = threadIdx.x;
  const float4* s4 = (const float4*)sumexp;
  const float4* d4 = (const float4*)diag;
  float s = 0.0f;
  for (int i = tid; i < N / 4; i += 1024) {
    float4 a = s4[i];
    float4 b = d4[i];
    s += (logf(a.x) - b.x) + (logf(a.y) - b.y) + (logf(a.z) - b.z) + (logf(a.w) - b.w);
  }
  #pragma unroll
  for (int off = 32; off > 0; off >>= 1) s += __shfl_down(s, off);
  __shared__ float red[16];
  if ((tid & 63) == 0) red[tid >> 6] = s;
  __syncthreads();
  if (tid == 0) {
    float t = 0.0f;
    #pragma unroll
    for (int i = 0; i < 16; ++i) t += red[i];
    out[0] = t / (float)N;
  }
}

extern "C" void kernel_launch(void* const* d_in, const int* in_sizes, int n_in,
                              void* d_out, int out_size, void* d_ws, size_t ws_size,
                              hipStream_t stream) {
  const int C = C_DIM;
  const int N = in_sizes[0] / C;  // 8192
  const float* pred   = (const float*)d_in[0];
  const float* target = (const float*)d_in[1];
  float* out = (float*)d_out;

  char* ws = (char*)d_ws;
  unsigned char* p8 = (unsigned char*)ws;                    // 4 MB fragment-tiled
  unsigned char* t8 = (unsigned char*)(ws + (size_t)N * C);  // 4 MB fragment-tiled
  float* diag   = (float*)(ws + (size_t)2 * N * C);
  float* sumexp = diag + N;

  cossim_normalize_v2<<<N, 128, 0, stream>>>(pred, target, p8, t8, diag, sumexp);
  const int nblk = (N / 128) * (N / 128);  // 4096
  cossim_gemm_lse_v2<<<nblk, 512, 0, stream>>>(p8, t8, sumexp);
  cossim_loss_v2<<<1, 1024, 0, stream>>>(sumexp, diag, out, N);
}